// Round 3
// baseline (396.487 us; speedup 1.0000x reference)
//
#include <hip/hip_runtime.h>
#include <hip/hip_bf16.h>

typedef __attribute__((ext_vector_type(8))) short short8;
typedef __attribute__((ext_vector_type(4))) float f32x4;
typedef __attribute__((ext_vector_type(2))) float f32x2;

// ---- workspace layout (bytes) ----
#define WS_ZE     0u           // bf16 hi  [B][N][64] : 1 MB
#define WS_ZELO   (1u<<20)     // bf16 lo  [B][N][64] : 1 MB
#define WS_B1H    (2u<<20)     // matmul1 A-frag image hi: (k*32+t)*2048 + frag*1024 + lane*16 : 1 MB
#define WS_B1L    (3u<<20)     // matmul1 A-frag image lo : 1 MB
#define WS_B2     (4u<<20)     // matmul2 A-frag image (hi): k*65536 + ((h*8+w)*4+m)*1024 + lane*16 : 1 MB
#define WS_ZN2    (5u<<20)     // f32 [B][N] 32 KB
#define WS_BS2    ((5u<<20)+32768u) // f32 [K][S] 32 KB

__device__ __forceinline__ unsigned short f2bf(float x) {
  __hip_bfloat16 h = __float2bfloat16(x);
  return __builtin_bit_cast(unsigned short, h);
}
__device__ __forceinline__ float bf2f(unsigned short u) {
  union { unsigned int i; float f; } x; x.i = ((unsigned int)u) << 16; return x.f;
}

// ---------------- prep: ze -> bf16 hi/lo + row norms ----------------
__global__ __launch_bounds__(256) void prep_ze_k(const float* __restrict__ ze,
                                                 char* __restrict__ ws) {
  int t = blockIdx.x * 256 + threadIdx.x;     // one per (b,n), 8192
  if (t >= 8 * 1024) return;
  const float* row = ze + t * 64;
  unsigned short* dh = (unsigned short*)(ws + WS_ZE) + t * 64;
  unsigned short* dl = (unsigned short*)(ws + WS_ZELO) + t * 64;
  float s = 0.f;
#pragma unroll 8
  for (int d = 0; d < 64; ++d) {
    float v = row[d]; s += v * v;
    unsigned short h = f2bf(v);
    dh[d] = h;
    dl[d] = f2bf(v - bf2f(h));
  }
  ((float*)(ws + WS_ZN2))[t] = s;
}

// ---------------- prep: books -> fragment-ordered bf16 images + norms + precision ----------------
__global__ __launch_bounds__(256) void prep_books_k(const float* __restrict__ books,
                                                    const float* __restrict__ lpq,
                                                    char* __restrict__ ws,
                                                    float* __restrict__ d_out) {
  int t = blockIdx.x * 256 + threadIdx.x;     // one per (k,s), 8192
  if (t == 0) d_out[524288] = 0.5f / fmaxf(expf(lpq[0]), 1e-10f);
  if (t >= 16 * 512) return;
  int k = t >> 9, s = t & 511;
  const float* row = books + t * 64;
  __align__(16) unsigned short hi16[64];
  __align__(16) unsigned short lo16[64];
  float sum = 0.f;
#pragma unroll 8
  for (int d = 0; d < 64; ++d) {
    float v = row[d]; sum += v * v;
    unsigned short h = f2bf(v);
    hi16[d] = h;
    lo16[d] = f2bf(v - bf2f(h));
  }
  ((float*)(ws + WS_BS2))[t] = sum;

  // --- matmul1 images: stile tt = s>>4, A-frag lane row = s&15.
  // lane l holds A-row l&15, k-elems (l>>4)*8+j  ->  this thread fills
  // chunks (s&15 + g*16) of frag f (d = f*32 + g*8 ..+8).
  const int tt = s >> 4, sl = s & 15;
  char* b1h = ws + WS_B1H + (k * 32 + tt) * 2048;
  char* b1l = ws + WS_B1L + (k * 32 + tt) * 2048;
#pragma unroll
  for (int f = 0; f < 2; ++f)
#pragma unroll
    for (int g = 0; g < 4; ++g) {
      *(short8*)(b1h + f * 1024 + (sl + g * 16) * 16) = *(const short8*)(hi16 + f * 32 + g * 8);
      *(short8*)(b1l + f * 1024 + (sl + g * 16) * 16) = *(const short8*)(lo16 + f * 32 + g * 8);
    }

  // --- matmul2 image (booksT, hi only): frag (h,w,m); lane l holds
  // d-row m*16 + (l&15), s-elems (l>>4)*8+j with s = h*256+w*32+(l>>4)*8+j.
  const int hh = s >> 8, w = (s >> 5) & 7, sub = (s >> 3) & 3, j7 = s & 7;
  char* b2 = ws + WS_B2 + (((k * 2 + hh) * 8 + w) * 4) * 1024;
#pragma unroll
  for (int m = 0; m < 4; ++m)
#pragma unroll
    for (int l15 = 0; l15 < 16; ++l15)
      *(unsigned short*)(b2 + m * 1024 + (l15 + sub * 16) * 16 + j7 * 2) = hi16[m * 16 + l15];
}

// ---------------- main ----------------
__global__ __launch_bounds__(512, 4)
void gvq_main(const float* __restrict__ gum, const float* __restrict__ cprobs,
              const float* __restrict__ lpq, const char* __restrict__ ws,
              float* __restrict__ d_out) {
  __shared__ char lds[49152];
  char* logitsb = lds;            // 32 KB f32 [16][512] swizzled
  char* encb    = lds + 32768;    // 16 KB bf16 [16][512] swizzled

  const int tid  = threadIdx.x;
  const int lane = tid & 63;
  const int wave = tid >> 6;       // 0..7
  const int l15  = lane & 15;
  const int g4   = lane >> 4;      // 0..3

  const int bid   = blockIdx.x;
  const int b     = bid >> 6;
  const int n0    = (bid & 63) * 16;

  const float prec = 0.5f / fmaxf(expf(lpq[0]), 1e-10f);

  const unsigned short* zh = (const unsigned short*)(ws + WS_ZE)   + (b * 1024 + n0 + l15) * 64;
  const unsigned short* zl = (const unsigned short*)(ws + WS_ZELO) + (b * 1024 + n0 + l15) * 64;
  const short8 zf0h = *(const short8*)(zh + g4 * 8);
  const short8 zf1h = *(const short8*)(zh + 32 + g4 * 8);
  const short8 zf0l = *(const short8*)(zl + g4 * 8);
  const short8 zf1l = *(const short8*)(zl + 32 + g4 * 8);
  const float zn2v = ((const float*)(ws + WS_ZN2))[b * 1024 + n0 + l15];
  const unsigned swzn_me = (unsigned)(l15 & 7) << 4;

  f32x4 zacc[4] = {{0,0,0,0},{0,0,0,0},{0,0,0,0},{0,0,0,0}};

#pragma unroll 1
  for (int k = 0; k < 16; ++k) {
    const float cp = cprobs[b * 16 + k];
    const char* b1h = ws + WS_B1H + k * 65536;
    const char* b1l = ws + WS_B1L + k * 65536;
    const char* b2  = ws + WS_B2  + k * 65536;
    const float* bs2k = (const float*)(ws + WS_BS2) + k * 512;

    // ---- phase A: logitsT via 3-term hi/lo bf16 MFMA; A-frags direct from L2 ----
#pragma unroll
    for (int i = 0; i < 4; ++i) {
      const int t = wave * 4 + i;                 // stile 0..31
      const int base = t * 2048 + lane * 16;
      const short8 a0h = *(const short8*)(b1h + base);
      const short8 a1h = *(const short8*)(b1h + base + 1024);
      const short8 a0l = *(const short8*)(b1l + base);
      const short8 a1l = *(const short8*)(b1l + base + 1024);
      f32x4 c = {0.f, 0.f, 0.f, 0.f};
      c = __builtin_amdgcn_mfma_f32_16x16x32_bf16(a0h, zf0h, c, 0, 0, 0);
      c = __builtin_amdgcn_mfma_f32_16x16x32_bf16(a1h, zf1h, c, 0, 0, 0);
      c = __builtin_amdgcn_mfma_f32_16x16x32_bf16(a0h, zf0l, c, 0, 0, 0);
      c = __builtin_amdgcn_mfma_f32_16x16x32_bf16(a1h, zf1l, c, 0, 0, 0);
      c = __builtin_amdgcn_mfma_f32_16x16x32_bf16(a0l, zf0h, c, 0, 0, 0);
      c = __builtin_amdgcn_mfma_f32_16x16x32_bf16(a1l, zf1h, c, 0, 0, 0);
      const f32x4 bs2v = *(const f32x4*)(bs2k + t * 16 + g4 * 4);
      f32x4 lg;
      lg.x = (2.f * c.x - zn2v - bs2v.x) * prec;
      lg.y = (2.f * c.y - zn2v - bs2v.y) * prec;
      lg.z = (2.f * c.z - zn2v - bs2v.z) * prec;
      lg.w = (2.f * c.w - zn2v - bs2v.w) * prec;
      *(f32x4*)(logitsb + l15 * 2048 + (((unsigned)(t * 64 + g4 * 16)) ^ swzn_me)) = lg;
    }
    __syncthreads();

    // ---- phase B: gumbel + two softmaxes; element s = j*64 + lane (coalesced) ----
#pragma unroll 1
    for (int r = 0; r < 2; ++r) {
      const int n = wave * 2 + r;
      const unsigned swzn = (unsigned)(n & 7) << 4;
      const char* lrow = logitsb + n * 2048;
      const long rowbase = ((long)((b * 16 + k) * 1024 + n0 + n)) * 512;
      const float* urow = gum + rowbase + lane;
      float lv[8], av[8];
#pragma unroll
      for (int j = 0; j < 8; ++j)
        lv[j] = *(const float*)(lrow + (((unsigned)(j * 256 + lane * 4)) ^ swzn));
      float m1 = -1e30f, m2 = -1e30f;
#pragma unroll
      for (int j = 0; j < 8; ++j) {
        const float u = urow[j * 64];
        const float gg = -__logf(-__logf(u + 1e-10f) + 1e-10f);
        av[j] = (lv[j] + gg) * 2.0f;          // /TEMPERATURE(0.5)
        m1 = fmaxf(m1, lv[j]); m2 = fmaxf(m2, av[j]);
      }
#pragma unroll
      for (int o = 32; o; o >>= 1) {
        m1 = fmaxf(m1, __shfl_xor(m1, o));
        m2 = fmaxf(m2, __shfl_xor(m2, o));
      }
      float e1v[8], z1 = 0.f, z2 = 0.f;
#pragma unroll
      for (int j = 0; j < 8; ++j) {
        lv[j] -= m1; av[j] -= m2;
        e1v[j] = __expf(lv[j]); z1 += e1v[j];
        av[j]  = __expf(av[j]); z2 += av[j];
      }
#pragma unroll
      for (int o = 32; o; o >>= 1) { z1 += __shfl_xor(z1, o); z2 += __shfl_xor(z2, o); }
      const float rz1 = 1.0f / z1;
      const float lz1 = __logf(z1);
      const float esc = cp / z2;               // fold c_probs into enc
      float* pp = d_out + 524289 + rowbase + lane;
      float* pl = pp + 67108864;
#pragma unroll
      for (int j = 0; j < 8; ++j) {
        pp[j * 64] = e1v[j] * rz1;
        pl[j * 64] = lv[j] - lz1;
      }
#pragma unroll
      for (int j = 0; j < 8; ++j)
        *(unsigned short*)(encb + n * 1024 + (((unsigned)(j * 128 + lane * 2)) ^ swzn)) =
            f2bf(av[j] * esc);
    }
    __syncthreads();

    // ---- phase C: zqT += booksT · encT; A-frags direct from L2 ----
#pragma unroll
    for (int h = 0; h < 2; ++h) {
      const short8 bf = *(const short8*)(encb + l15 * 1024 +
          (((unsigned)(h * 512 + wave * 64 + g4 * 16)) ^ swzn_me));
#pragma unroll
      for (int m = 0; m < 4; ++m) {
        const short8 af = *(const short8*)(b2 + ((h * 8 + wave) * 4 + m) * 1024 + lane * 16);
        zacc[m] = __builtin_amdgcn_mfma_f32_16x16x32_bf16(af, bf, zacc[m], 0, 0, 0);
      }
    }
    // no barrier: next phase A touches logitsb only; encb rewritten only after next barrier
  }

  // ---- zq cross-wave reduce + write ----
#pragma unroll
  for (int m = 0; m < 4; ++m)
    *(f32x4*)(logitsb + wave * 4096 + l15 * 256 + m * 64 + g4 * 16) = zacc[m];
  __syncthreads();
  const int e = tid * 2;                    // 0..1022, covers 16*64 elems
  f32x2 acc = {0.f, 0.f};
#pragma unroll
  for (int w = 0; w < 8; ++w) acc += *(const f32x2*)(logitsb + w * 4096 + e * 4);
  *(f32x2*)(d_out + ((long)(b * 1024 + n0)) * 64 + e) = acc;
}

extern "C" void kernel_launch(void* const* d_in, const int* in_sizes, int n_in,
                              void* d_out, int out_size, void* d_ws, size_t ws_size,
                              hipStream_t stream) {
  (void)in_sizes; (void)n_in; (void)out_size; (void)ws_size;
  const float* ze     = (const float*)d_in[0];
  const float* cprobs = (const float*)d_in[1];
  const float* books  = (const float*)d_in[2];
  const float* lpq    = (const float*)d_in[3];
  const float* gum    = (const float*)d_in[4];
  float* out = (float*)d_out;
  char* ws = (char*)d_ws;
  hipLaunchKernelGGL(prep_ze_k,    dim3(32),  dim3(256), 0, stream, ze, ws);
  hipLaunchKernelGGL(prep_books_k, dim3(32),  dim3(256), 0, stream, books, lpq, ws, out);
  hipLaunchKernelGGL(gvq_main,     dim3(512), dim3(512), 0, stream, gum, cprobs, lpq, ws, out);
}

// Round 5
// 327.614 us; speedup vs baseline: 1.2102x; 1.2102x over previous
//
#include <hip/hip_runtime.h>
#include <hip/hip_bf16.h>

typedef __attribute__((ext_vector_type(8))) short short8;
typedef __attribute__((ext_vector_type(4))) float f32x4;
typedef __attribute__((ext_vector_type(2))) float f32x2;
typedef __attribute__((ext_vector_type(4))) unsigned short us4;

// ---- workspace layout (bytes) ----
#define WS_ZE     0u           // bf16 hi  [B][N][64] : 1 MB
#define WS_ZELO   (1u<<20)     // bf16 lo  [B][N][64] : 1 MB
#define WS_B1H    (2u<<20)     // matmul1 A-frag image hi: (k*32+t)*2048 + frag*1024 + lane*16 : 1 MB
#define WS_B1L    (3u<<20)     // matmul1 A-frag image lo : 1 MB
#define WS_B2     (4u<<20)     // matmul2 A-frag image (hi): k*65536 + ((h*8+w)*4+m)*1024 + lane*16 : 1 MB
#define WS_ZN2    (5u<<20)     // f32 [B][N] 32 KB
#define WS_BS2    ((5u<<20)+32768u) // f32 [K][S] 32 KB

__device__ __forceinline__ unsigned short f2bf(float x) {
  __hip_bfloat16 h = __float2bfloat16(x);
  return __builtin_bit_cast(unsigned short, h);
}
__device__ __forceinline__ float bf2f(unsigned short u) {
  union { unsigned int i; float f; } x; x.i = ((unsigned int)u) << 16; return x.f;
}

// ---------------- prep: ze -> bf16 hi/lo + row norms ----------------
__global__ __launch_bounds__(256) void prep_ze_k(const float* __restrict__ ze,
                                                 char* __restrict__ ws) {
  int t = blockIdx.x * 256 + threadIdx.x;     // one per (b,n), 8192
  if (t >= 8 * 1024) return;
  const float* row = ze + t * 64;
  unsigned short* dh = (unsigned short*)(ws + WS_ZE) + t * 64;
  unsigned short* dl = (unsigned short*)(ws + WS_ZELO) + t * 64;
  float s = 0.f;
#pragma unroll 8
  for (int d = 0; d < 64; ++d) {
    float v = row[d]; s += v * v;
    unsigned short h = f2bf(v);
    dh[d] = h;
    dl[d] = f2bf(v - bf2f(h));
  }
  ((float*)(ws + WS_ZN2))[t] = s;
}

// ---------------- prep: books -> fragment-ordered bf16 images + norms + precision ----------------
__global__ __launch_bounds__(256) void prep_books_k(const float* __restrict__ books,
                                                    const float* __restrict__ lpq,
                                                    char* __restrict__ ws,
                                                    float* __restrict__ d_out) {
  int t = blockIdx.x * 256 + threadIdx.x;     // one per (k,s), 8192
  if (t == 0) d_out[524288] = 0.5f / fmaxf(expf(lpq[0]), 1e-10f);
  if (t >= 16 * 512) return;
  int k = t >> 9, s = t & 511;
  const float* row = books + t * 64;
  __align__(16) unsigned short hi16[64];
  __align__(16) unsigned short lo16[64];
  float sum = 0.f;
#pragma unroll 8
  for (int d = 0; d < 64; ++d) {
    float v = row[d]; sum += v * v;
    unsigned short h = f2bf(v);
    hi16[d] = h;
    lo16[d] = f2bf(v - bf2f(h));
  }
  ((float*)(ws + WS_BS2))[t] = sum;

  // --- matmul1 images: stile tt = s>>4, A-frag lane row = s&15.
  const int tt = s >> 4, sl = s & 15;
  char* b1h = ws + WS_B1H + (k * 32 + tt) * 2048;
  char* b1l = ws + WS_B1L + (k * 32 + tt) * 2048;
#pragma unroll
  for (int f = 0; f < 2; ++f)
#pragma unroll
    for (int g = 0; g < 4; ++g) {
      *(short8*)(b1h + f * 1024 + (sl + g * 16) * 16) = *(const short8*)(hi16 + f * 32 + g * 8);
      *(short8*)(b1l + f * 1024 + (sl + g * 16) * 16) = *(const short8*)(lo16 + f * 32 + g * 8);
    }

  // --- matmul2 image (booksT, hi only): frag (h,w,m); lane l holds
  // d-row m*16 + (l&15), s-elems (l>>4)*8+j with s = h*256+w*32+(l>>4)*8+j.
  const int hh = s >> 8, w = (s >> 5) & 7, sub = (s >> 3) & 3, j7 = s & 7;
  char* b2 = ws + WS_B2 + (((k * 2 + hh) * 8 + w) * 4) * 1024;
#pragma unroll
  for (int m = 0; m < 4; ++m)
#pragma unroll
    for (int l15 = 0; l15 < 16; ++l15)
      *(unsigned short*)(b2 + m * 1024 + (l15 + sub * 16) * 16 + j7 * 2) = hi16[m * 16 + l15];
}

// ---------------- main ----------------
__global__ __launch_bounds__(512, 4)
void gvq_main(const float* __restrict__ gum, const float* __restrict__ cprobs,
              const float* __restrict__ lpq, const char* __restrict__ ws,
              float* __restrict__ d_out) {
  __shared__ char lds[32768];
  char* encb  = lds;                          // 16 KB bf16 [16][512] swizzled rows
  f32x2* mscr = (f32x2*)(lds + 16384);        // [8 waves][16 n]
  f32x2* zscr = (f32x2*)(lds + 17408);        // [8 waves][16 n]

  const int tid  = threadIdx.x;
  const int lane = tid & 63;
  const int wave = tid >> 6;       // 0..7
  const int l15  = lane & 15;      // = n within tile (MFMA D col)
  const int g4   = lane >> 4;      // 0..3

  const int bid = blockIdx.x;
  const int b   = bid >> 6;
  const int n0  = (bid & 63) * 16;

  const float prec  = 0.5f / fmaxf(expf(lpq[0]), 1e-10f);
  const float prec2 = 2.0f * prec;

  const unsigned short* zh = (const unsigned short*)(ws + WS_ZE)   + (b * 1024 + n0 + l15) * 64;
  const unsigned short* zl = (const unsigned short*)(ws + WS_ZELO) + (b * 1024 + n0 + l15) * 64;
  const short8 zf0h = *(const short8*)(zh + g4 * 8);
  const short8 zf1h = *(const short8*)(zh + 32 + g4 * 8);
  const short8 zf0l = *(const short8*)(zl + g4 * 8);
  const short8 zf1l = *(const short8*)(zl + 32 + g4 * 8);
  const float zn2p = ((const float*)(ws + WS_ZN2))[b * 1024 + n0 + l15] * prec;

  const unsigned swzr = (unsigned)(l15 & 7) << 4;
  char* encrow = encb + l15 * 1024;

  f32x4 zacc[4] = {{0,0,0,0},{0,0,0,0},{0,0,0,0},{0,0,0,0}};

  // element layout per lane: s = wave*64 + i*16 + g4*4 + reg  (16 elems, n = l15)
  const long gbase0 = ((long)(b * 16) * 1024 + (n0 + l15)) * 512 + wave * 64 + g4 * 4;

#pragma unroll 1
  for (int k = 0; k < 16; ++k) {
    const float cp = cprobs[b * 16 + k];
    const char* b1h = ws + WS_B1H + k * 65536;
    const char* b1l = ws + WS_B1L + k * 65536;
    const char* b2  = ws + WS_B2  + k * 65536;
    const float* bs2k = (const float*)(ws + WS_BS2) + k * 512;
    const long gb = gbase0 + (long)k * 524288;

    // ---- gumbel loads for this iter (land under phase A) ----
    const float* up = gum + gb;
    f32x4 uu[4];
#pragma unroll
    for (int i = 0; i < 4; ++i) uu[i] = *(const f32x4*)(up + i * 16);

    // ---- phase A: logits in registers (3-term hi/lo bf16 MFMA) ----
    f32x4 lv[4];
#pragma unroll
    for (int i = 0; i < 4; ++i) {
      const int t = wave * 4 + i;                 // stile 0..31
      const char* bh = b1h + t * 2048 + lane * 16;
      const char* bl = b1l + t * 2048 + lane * 16;
      const short8 a0h = *(const short8*)(bh);
      const short8 a1h = *(const short8*)(bh + 1024);
      const short8 a0l = *(const short8*)(bl);
      const short8 a1l = *(const short8*)(bl + 1024);
      f32x4 c = {0.f, 0.f, 0.f, 0.f};
      c = __builtin_amdgcn_mfma_f32_16x16x32_bf16(a0h, zf0h, c, 0, 0, 0);
      c = __builtin_amdgcn_mfma_f32_16x16x32_bf16(a1h, zf1h, c, 0, 0, 0);
      c = __builtin_amdgcn_mfma_f32_16x16x32_bf16(a0h, zf0l, c, 0, 0, 0);
      c = __builtin_amdgcn_mfma_f32_16x16x32_bf16(a1h, zf1l, c, 0, 0, 0);
      c = __builtin_amdgcn_mfma_f32_16x16x32_bf16(a0l, zf0h, c, 0, 0, 0);
      c = __builtin_amdgcn_mfma_f32_16x16x32_bf16(a1l, zf1h, c, 0, 0, 0);
      const f32x4 bs2v = *(const f32x4*)(bs2k + t * 16 + g4 * 4);
#pragma unroll
      for (int r = 0; r < 4; ++r)
        lv[i][r] = fmaf(c[r], prec2, fmaf(bs2v[r], -prec, -zn2p));
    }

    // ---- pass 1: gumbel transform + maxes ----
    f32x4 av[4];
    float m1 = -1e30f, m2 = -1e30f;
#pragma unroll
    for (int i = 0; i < 4; ++i)
#pragma unroll
      for (int r = 0; r < 4; ++r) {
        const float gg = -__logf(-__logf(uu[i][r] + 1e-10f) + 1e-10f);
        const float a = (lv[i][r] + gg) * 2.0f;     // /TEMPERATURE(0.5)
        av[i][r] = a;
        m1 = fmaxf(m1, lv[i][r]);
        m2 = fmaxf(m2, a);
      }
    m1 = fmaxf(m1, __shfl_xor(m1, 16)); m1 = fmaxf(m1, __shfl_xor(m1, 32));
    m2 = fmaxf(m2, __shfl_xor(m2, 16)); m2 = fmaxf(m2, __shfl_xor(m2, 32));
    if (g4 == 0) mscr[wave * 16 + l15] = (f32x2){m1, m2};
    __syncthreads();
    {
      const f32x2 pa = mscr[g4 * 16 + l15];
      const f32x2 pb = mscr[(g4 + 4) * 16 + l15];
      m1 = fmaxf(pa.x, pb.x); m2 = fmaxf(pa.y, pb.y);
      m1 = fmaxf(m1, __shfl_xor(m1, 16)); m1 = fmaxf(m1, __shfl_xor(m1, 32));
      m2 = fmaxf(m2, __shfl_xor(m2, 16)); m2 = fmaxf(m2, __shfl_xor(m2, 32));
    }

    // ---- pass 2: exps + sums ----
    f32x4 e1[4];
    float z1 = 0.f, z2 = 0.f;
#pragma unroll
    for (int i = 0; i < 4; ++i)
#pragma unroll
      for (int r = 0; r < 4; ++r) {
        const float e = __expf(lv[i][r] - m1); e1[i][r] = e; z1 += e;
        const float f = __expf(av[i][r] - m2); av[i][r] = f; z2 += f;
      }
    z1 += __shfl_xor(z1, 16); z1 += __shfl_xor(z1, 32);
    z2 += __shfl_xor(z2, 16); z2 += __shfl_xor(z2, 32);
    if (g4 == 0) zscr[wave * 16 + l15] = (f32x2){z1, z2};
    __syncthreads();
    {
      const f32x2 pa = zscr[g4 * 16 + l15];
      const f32x2 pb = zscr[(g4 + 4) * 16 + l15];
      z1 = pa.x + pb.x; z2 = pa.y + pb.y;
      z1 += __shfl_xor(z1, 16); z1 += __shfl_xor(z1, 32);
      z2 += __shfl_xor(z2, 16); z2 += __shfl_xor(z2, 32);
    }
    const float rz1 = 1.0f / z1;
    const float lz1 = __logf(z1);
    const float esc = cp / z2;                     // fold c_probs into enc

    // ---- finish: stores + enc pack ----
    float* pp = d_out + 524289 + gb;
    float* pl = pp + 67108864;
#pragma unroll
    for (int i = 0; i < 4; ++i) {
      f32x4 pv, lpv;
#pragma unroll
      for (int r = 0; r < 4; ++r) {
        pv[r]  = e1[i][r] * rz1;
        lpv[r] = (lv[i][r] - m1) - lz1;
      }
      *(f32x4*)(pp + i * 16) = pv;
      *(f32x4*)(pl + i * 16) = lpv;
      us4 ev;
#pragma unroll
      for (int r = 0; r < 4; ++r) ev[r] = f2bf(av[i][r] * esc);
      *(us4*)(encrow + (((unsigned)(wave * 128 + i * 32 + g4 * 8)) ^ swzr)) = ev;
    }
    __syncthreads();   // enc ready for all waves

    // ---- phase C: zqT += booksT · encT; A-frags direct from L2 ----
#pragma unroll
    for (int h = 0; h < 2; ++h) {
      const short8 bf = *(const short8*)(encrow +
          (((unsigned)(h * 512 + wave * 64 + g4 * 16)) ^ swzr));
#pragma unroll
      for (int m = 0; m < 4; ++m) {
        const short8 af = *(const short8*)(b2 + ((h * 8 + wave) * 4 + m) * 1024 + lane * 16);
        zacc[m] = __builtin_amdgcn_mfma_f32_16x16x32_bf16(af, bf, zacc[m], 0, 0, 0);
      }
    }
    // next iter's encb writes are after its two reduce barriers -> C reads safe
  }

  // ---- zq cross-wave reduce + write (reuse full 32 KB LDS) ----
  __syncthreads();
#pragma unroll
  for (int m = 0; m < 4; ++m)
    *(f32x4*)(lds + wave * 4096 + l15 * 256 + m * 64 + g4 * 16) = zacc[m];
  __syncthreads();
  const int e = tid * 2;                    // 0..1022, covers 16*64 elems
  f32x2 acc = {0.f, 0.f};
#pragma unroll
  for (int w = 0; w < 8; ++w) acc += *(const f32x2*)(lds + w * 4096 + e * 4);
  *(f32x2*)(d_out + ((long)(b * 1024 + n0)) * 64 + e) = acc;
}

extern "C" void kernel_launch(void* const* d_in, const int* in_sizes, int n_in,
                              void* d_out, int out_size, void* d_ws, size_t ws_size,
                              hipStream_t stream) {
  (void)in_sizes; (void)n_in; (void)out_size; (void)ws_size;
  const float* ze     = (const float*)d_in[0];
  const float* cprobs = (const float*)d_in[1];
  const float* books  = (const float*)d_in[2];
  const float* lpq    = (const float*)d_in[3];
  const float* gum    = (const float*)d_in[4];
  float* out = (float*)d_out;
  char* ws = (char*)d_ws;
  hipLaunchKernelGGL(prep_ze_k,    dim3(32),  dim3(256), 0, stream, ze, ws);
  hipLaunchKernelGGL(prep_books_k, dim3(32),  dim3(256), 0, stream, books, lpq, ws, out);
  hipLaunchKernelGGL(gvq_main,     dim3(512), dim3(512), 0, stream, gum, cprobs, lpq, ws, out);
}